// Round 7
// baseline (328.029 us; speedup 1.0000x reference)
//
#include <hip/hip_runtime.h>
#include <hip/hip_bf16.h>

typedef __attribute__((ext_vector_type(8))) short bf16x8;
typedef __attribute__((ext_vector_type(4))) float f32x4;

#define NPTS 8192
#define KNB  16
#define CG   10
#define CIN  128
#define CC   256
#define COUT 256
#define PB   4        // points per block
#define A2_LD 400     // a2S pitch in bf16 (800 B -> 8-dword bank stagger per row)

// d_ws layout (bytes)
#define WSA_OFF 0         // w_attn frags: 256x256 bf16 = 131072
#define WSB_OFF 131072    // W2 frags:    384x256 bf16 = 196608
#define DD_OFF  327680    // dd[256] fp32 = 1024
#define WN_OFF  328704    // w_n frags (an-folded, K=32 zero-pad): 8x64x8 bf16 = 8192
#define DN_OFF  336896    // dn_n[128] fp32 = 512
#define FB_OFF  524288    // featbf: 32768 x 128 bf16 = 8388608
#define RA_OFF  8912896   // rawA: 524288 rows x 32 bf16 (A-layout, K-pad) = 33554432
#define WS_FB   (FB_OFF + 8388608ull)
#define WS_RA   (RA_OFF + 33554432ull)

__device__ __forceinline__ short f2bs(float x) {
    __hip_bfloat16 h = __float2bfloat16(x);
    return *reinterpret_cast<short*>(&h);
}

// ---------------- pre: featbf cvt + rawA cvt + weight fragment packing ----------------
__global__ __launch_bounds__(256) void lfa_pre(
    const float* __restrict__ feature, const float* __restrict__ rawn,
    const float* __restrict__ w_attn,
    const float* __restrict__ w_n, const float* __restrict__ b_n,
    const float* __restrict__ g_n, const float* __restrict__ beta_n,
    const float* __restrict__ rm_n, const float* __restrict__ rv_n,
    const float* __restrict__ w_o, const float* __restrict__ b_o,
    const float* __restrict__ g_o, const float* __restrict__ beta_o,
    const float* __restrict__ rm_o, const float* __restrict__ rv_o,
    const float* __restrict__ w_s, const float* __restrict__ b_s,
    const float* __restrict__ g_s, const float* __restrict__ beta_s,
    const float* __restrict__ rm_s, const float* __restrict__ rv_s,
    __hip_bfloat16* __restrict__ featbf, __hip_bfloat16* __restrict__ rawA,
    __hip_bfloat16* __restrict__ wsA, __hip_bfloat16* __restrict__ wsB,
    float* __restrict__ dd,
    __hip_bfloat16* __restrict__ wsN, float* __restrict__ dnw,
    int use_fb, int use_ra)
{
    const int b = blockIdx.x, tid = threadIdx.x;
    if (b < 2048) {                      // featbf: fp32 -> bf16, 8 elems/thread
        if (!use_fb) return;
        size_t gid = (size_t)b * 256 + tid;
        const float4* src = (const float4*)(feature + gid * 8);
        float4 x = src[0], y = src[1];
        bf16x8 v;
        v[0] = f2bs(x.x); v[1] = f2bs(x.y); v[2] = f2bs(x.z); v[3] = f2bs(x.w);
        v[4] = f2bs(y.x); v[5] = f2bs(y.y); v[6] = f2bs(y.z); v[7] = f2bs(y.w);
        *(bf16x8*)(featbf + gid * 8) = v;
        return;
    }
    if (b < 4096) {                      // rawA: one (point,k) row per thread, K-pad to 32
        if (!use_ra) return;
        size_t row = (size_t)(b - 2048) * 256 + tid;     // 524288 rows
        const float* rb = rawn + row * CG;
        bf16x8 v0, v1, vz;
        #pragma unroll
        for (int j = 0; j < 8; ++j) vz[j] = 0;
        float2 a0 = *(const float2*)(rb + 0), a1 = *(const float2*)(rb + 2);
        float2 a2 = *(const float2*)(rb + 4), a3 = *(const float2*)(rb + 6);
        float2 a4 = *(const float2*)(rb + 8);
        v0[0] = f2bs(a0.x); v0[1] = f2bs(a0.y); v0[2] = f2bs(a1.x); v0[3] = f2bs(a1.y);
        v0[4] = f2bs(a2.x); v0[5] = f2bs(a2.y); v0[6] = f2bs(a3.x); v0[7] = f2bs(a3.y);
        v1 = vz; v1[0] = f2bs(a4.x); v1[1] = f2bs(a4.y);
        bf16x8* dst = (bf16x8*)(rawA + row * 32);
        dst[0] = v0; dst[1] = v1; dst[2] = vz; dst[3] = vz;
        return;
    }
    int gid = (b - 4096) * 256 + tid;    // weight packing
    if (gid < 8192) {                    // w_attn: 128 frags (kt 0..7, nt 0..15)
        int f = gid >> 6, l = gid & 63;
        int kt = f >> 4, nt = f & 15, q = l >> 4, c0 = l & 15;
        int col = nt * 16 + c0;
        bf16x8 v;
        #pragma unroll
        for (int j = 0; j < 8; ++j)
            v[j] = f2bs(w_attn[(kt * 32 + q * 8 + j) * CC + col]);
        *(bf16x8*)(wsA + (size_t)gid * 8) = v;
    } else if (gid < 8192 + 12288) {     // W2 = [w_s*a_s ; w_o*a_o]: 192 frags
        int g2 = gid - 8192;
        int f = g2 >> 6, l = g2 & 63;
        int kt = f >> 4, nt = f & 15, q = l >> 4, c0 = l & 15;
        int c = nt * 16 + c0;
        float as = g_s[c] * rsqrtf(rv_s[c] + 1e-5f);
        float ao = g_o[c] * rsqrtf(rv_o[c] + 1e-5f);
        bf16x8 v;
        #pragma unroll
        for (int j = 0; j < 8; ++j) {
            int r = kt * 32 + q * 8 + j;
            float x = (r < CIN) ? w_s[r * COUT + c] * as
                                : w_o[(r - CIN) * COUT + c] * ao;
            v[j] = f2bs(x);
        }
        *(bf16x8*)(wsB + (size_t)g2 * 8) = v;
    } else if (gid < 20736) {            // dd[c]
        int c = gid - 20480;
        float as = g_s[c] * rsqrtf(rv_s[c] + 1e-5f);
        float ao = g_o[c] * rsqrtf(rv_o[c] + 1e-5f);
        dd[c] = beta_s[c] + (b_s[c] - rm_s[c]) * as
              + beta_o[c] + (b_o[c] - rm_o[c]) * ao;
    } else if (gid < 21248) {            // w_n frags: an folded, K zero-pad to 32
        int g3 = gid - 20736;
        int nt = g3 >> 6, l = g3 & 63;
        int q = l >> 4, c0 = l & 15;
        int n = nt * 16 + c0;
        float an = g_n[n] * rsqrtf(rv_n[n] + 1e-5f);
        bf16x8 v;
        #pragma unroll
        for (int j = 0; j < 8; ++j) {
            int k = q * 8 + j;
            v[j] = (k < CG) ? f2bs(w_n[k * 128 + n] * an) : (short)0;
        }
        *(bf16x8*)(wsN + (size_t)g3 * 8) = v;
    } else if (gid < 21376) {            // dn_n[c]
        int c = gid - 21248;
        float an = g_n[c] * rsqrtf(rv_n[c] + 1e-5f);
        dnw[c] = beta_n[c] + (b_n[c] - rm_n[c]) * an;
    }
}

// ---------------- main fused kernel: PB points per block, 4 waves ----------------
// launch_bounds(256,3): 3 waves/EU -> ~170 VGPR budget; (256,4) spilled to scratch
// (r6: WRITE_SIZE 310 MB vs 33 MB real output -> spill traffic saturated HBM)
__global__ __launch_bounds__(256, 3) void lfa_main(
    const float* __restrict__ feature,   // [B,N,CIN] fp32
    const float* __restrict__ rawn,      // [B,N,K,CG]
    const int*   __restrict__ nidx,      // [B,N,K]
    const __hip_bfloat16* __restrict__ wsA,
    const __hip_bfloat16* __restrict__ wsB,
    const float* __restrict__ dd,
    const __hip_bfloat16* __restrict__ wsN,
    const float* __restrict__ dnw,
    const __hip_bfloat16* __restrict__ featbf,
    const __hip_bfloat16* __restrict__ rawA,
    int use_fb, int use_ra,
    float* __restrict__ out)             // [B,N,COUT]
{
    // catS: [64 rows][256 bf16], XOR-swizzled 16B chunks: chunk_phys = chunk ^ (row&7)
    __shared__ __align__(16) __hip_bfloat16 catS[64 * 256];   // 32768 B
    __shared__ __align__(16) __hip_bfloat16 a2S[4 * A2_LD];   // 3200 B

    const int tid  = threadIdx.x;
    const int lane = tid & 63;
    const int w    = tid >> 6;     // wave id 0..3
    const int q    = lane >> 4;    // quad 0..3
    const int c0   = lane & 15;
    const long long base0 = (long long)blockIdx.x * PB;   // identity mapping
    const long long bIdx  = base0 >> 13;                  // batch index (N=8192)

    // ---- prefetch neighbor-MLP operands (in flight during staging)
    bf16x8 wnb[2];
    #pragma unroll
    for (int i = 0; i < 2; ++i)
        wnb[i] = *(const bf16x8*)(wsN + (size_t)(((2 * w + i) * 64 + lane) * 8));
    bf16x8 am[4];
    if (use_ra) {
        #pragma unroll
        for (int mt = 0; mt < 4; ++mt)
            am[mt] = *(const bf16x8*)(rawA + (size_t)(base0 * 16 + mt * 16 + c0) * 32 + q * 8);
    } else {
        #pragma unroll
        for (int mt = 0; mt < 4; ++mt) {
            bf16x8 v;
            #pragma unroll
            for (int j = 0; j < 8; ++j) v[j] = 0;
            if (q == 0) {
                const float* rb = rawn + ((base0 + mt) * KNB + c0) * CG;
                #pragma unroll
                for (int j = 0; j < 8; ++j) v[j] = f2bs(rb[j]);
            } else if (q == 1) {
                const float* rb = rawn + ((base0 + mt) * KNB + c0) * CG + 8;
                v[0] = f2bs(rb[0]); v[1] = f2bs(rb[1]);
            }
            am[mt] = v;
        }
    }

    // ---- phase 0b: center features -> a2S rows 0..3, cols 0..127
    if (use_fb) {
        if (tid < 64) {
            int p = tid >> 4, ch = tid & 15;
            *(bf16x8*)&a2S[p * A2_LD + ch * 8] =
                *(const bf16x8*)(featbf + (base0 + p) * CIN + ch * 8);
        }
    } else {
        int p = tid >> 6, cc = (tid & 63) * 2;
        const float* src = feature + (base0 + p) * CIN + cc;
        a2S[p * A2_LD + cc]     = __float2bfloat16(src[0]);
        a2S[p * A2_LD + cc + 1] = __float2bfloat16(src[1]);
    }
    // ---- phase 0c: gather neighbor features -> catS cols 0..127
    {
        int row = tid >> 2, qd = tid & 3;            // 64 rows x 4 quarters
        int ridx = nidx[base0 * KNB + row];          // 4-way dup -> L2 broadcast
        int sw = row & 7;
        if (use_fb) {
            const bf16x8* src = (const bf16x8*)(featbf + (bIdx * NPTS + ridx) * CIN + qd * 32);
            #pragma unroll
            for (int j = 0; j < 4; ++j)
                *(bf16x8*)&catS[row * 256 + (((qd * 4 + j) ^ sw) << 3)] = src[j];
        } else {
            const float4* src = (const float4*)(feature + (bIdx * NPTS + ridx) * CIN + qd * 32);
            #pragma unroll
            for (int j = 0; j < 4; ++j) {
                float4 x = src[2 * j], y = src[2 * j + 1];
                bf16x8 v;
                v[0] = f2bs(x.x); v[1] = f2bs(x.y); v[2] = f2bs(x.z); v[3] = f2bs(x.w);
                v[4] = f2bs(y.x); v[5] = f2bs(y.y); v[6] = f2bs(y.z); v[7] = f2bs(y.w);
                *(bf16x8*)&catS[row * 256 + (((qd * 4 + j) ^ sw) << 3)] = v;
            }
        }
    }

    // ---- phase 0d: neighbor MLP via MFMA -> catS cols 128..255
    {
        const f32x4 vz = {0.f, 0.f, 0.f, 0.f};
        f32x4 cm[4][2];
        #pragma unroll
        for (int mt = 0; mt < 4; ++mt) { cm[mt][0] = vz; cm[mt][1] = vz; }
        #pragma unroll
        for (int mt = 0; mt < 4; ++mt)
            #pragma unroll
            for (int i = 0; i < 2; ++i)
                cm[mt][i] = __builtin_amdgcn_mfma_f32_16x16x32_bf16(am[mt], wnb[i], cm[mt][i], 0, 0, 0);
        #pragma unroll
        for (int i = 0; i < 2; ++i) {
            int c = (2 * w + i) * 16 + c0;      // MLP out channel 0..127
            float dnv = dnw[c];
            int col = CIN + c;
            #pragma unroll
            for (int mt = 0; mt < 4; ++mt)
                #pragma unroll
                for (int r = 0; r < 4; ++r) {
                    float y = cm[mt][i][r] + dnv;
                    y = (y >= 0.f) ? y : 0.2f * y;
                    int row = mt * 16 + q * 4 + r;
                    catS[row * 256 + ((((col >> 3) ^ (row & 7)) << 3)) + (col & 7)] =
                        __float2bfloat16(y);
                }
        }
    }
    __syncthreads();

    // ---- phase 1: logits GEMM  C[64 x 256] = cat[64 x 256] @ w_attn[256 x 256]
    const f32x4 vzero = {0.f, 0.f, 0.f, 0.f};
    f32x4 acc[4][4];
    #pragma unroll
    for (int mt = 0; mt < 4; ++mt)
        #pragma unroll
        for (int i = 0; i < 4; ++i) acc[mt][i] = vzero;

    #pragma unroll
    for (int kt = 0; kt < 8; ++kt) {
        bf16x8 bfr[4];
        #pragma unroll
        for (int i = 0; i < 4; ++i)
            bfr[i] = *(const bf16x8*)(wsA + (size_t)(((kt * 16 + 4 * w + i) * 64 + lane) * 8));
        bf16x8 af[4];
        #pragma unroll
        for (int mt = 0; mt < 4; ++mt)
            af[mt] = *(const bf16x8*)&catS[(mt * 16 + c0) * 256 + (((kt * 4 + q) ^ (c0 & 7)) << 3)];
        #pragma unroll
        for (int mt = 0; mt < 4; ++mt)
            #pragma unroll
            for (int i = 0; i < 4; ++i)
                acc[mt][i] = __builtin_amdgcn_mfma_f32_16x16x32_bf16(af[mt], bfr[i], acc[mt][i], 0, 0, 0);
    }

    // ---- phase 2: softmax over k (no max-sub; logits ~N(0,1)) + pooling
    // C layout: col = lane&15, row = q*4 + reg
    #pragma unroll
    for (int mt = 0; mt < 4; ++mt) {
        #pragma unroll
        for (int i = 0; i < 4; ++i) {
            f32x4 v = acc[mt][i];
            float e[4], s = 0.f;
            #pragma unroll
            for (int r = 0; r < 4; ++r) { e[r] = __expf(v[r]); s += e[r]; }
            s += __shfl_xor(s, 16);
            s += __shfl_xor(s, 32);
            int c = (4 * w + i) * 16 + c0;
            float pool = 0.f;
            #pragma unroll
            for (int r = 0; r < 4; ++r) {
                int row = mt * 16 + q * 4 + r;
                float cv = __bfloat162float(
                    catS[row * 256 + ((((c >> 3) ^ (row & 7)) << 3)) + (c & 7)]);
                pool += e[r] * cv;
            }
            pool += __shfl_xor(pool, 16);
            pool += __shfl_xor(pool, 32);
            if (q == mt) a2S[mt * A2_LD + CIN + c] = __float2bfloat16(pool / s);
        }
    }
    __syncthreads();

    // ---- phase 3: out GEMM  [4 x 256] = [feat|pooled][4 x 384] @ W2[384 x 256]
    f32x4 acc2[4];
    #pragma unroll
    for (int i = 0; i < 4; ++i) acc2[i] = vzero;
    #pragma unroll
    for (int kt = 0; kt < 12; ++kt) {
        bf16x8 a = *(const bf16x8*)&a2S[(c0 & 3) * A2_LD + kt * 32 + q * 8];
        #pragma unroll
        for (int i = 0; i < 4; ++i) {
            bf16x8 b = *(const bf16x8*)(wsB + (size_t)(((kt * 16 + 4 * w + i) * 64 + lane) * 8));
            acc2[i] = __builtin_amdgcn_mfma_f32_16x16x32_bf16(a, b, acc2[i], 0, 0, 0);
        }
    }
    // full-wave epilogue: quad q writes point q (select reg r=q)
    #pragma unroll
    for (int i = 0; i < 4; ++i) {
        int c = (4 * w + i) * 16 + c0;
        f32x4 t = acc2[i];
        float y = (q & 2) ? ((q & 1) ? t[3] : t[2]) : ((q & 1) ? t[1] : t[0]);
        y += dd[c];
        y = (y >= 0.f) ? y : 0.2f * y;
        out[(base0 + q) * COUT + c] = y;
    }
}

extern "C" void kernel_launch(void* const* d_in, const int* in_sizes, int n_in,
                              void* d_out, int out_size, void* d_ws, size_t ws_size,
                              hipStream_t stream) {
    const float* feature = (const float*)d_in[0];
    const float* rawn    = (const float*)d_in[1];
    const int*   nidx    = (const int*)d_in[2];
    const float* w_n     = (const float*)d_in[3];
    const float* b_n     = (const float*)d_in[4];
    const float* g_n     = (const float*)d_in[5];
    const float* beta_n  = (const float*)d_in[6];
    const float* rm_n    = (const float*)d_in[7];
    const float* rv_n    = (const float*)d_in[8];
    const float* w_attn  = (const float*)d_in[9];
    const float* w_o     = (const float*)d_in[10];
    const float* b_o     = (const float*)d_in[11];
    const float* g_o     = (const float*)d_in[12];
    const float* beta_o  = (const float*)d_in[13];
    const float* rm_o    = (const float*)d_in[14];
    const float* rv_o    = (const float*)d_in[15];
    const float* w_s     = (const float*)d_in[16];
    const float* b_s     = (const float*)d_in[17];
    const float* g_s     = (const float*)d_in[18];
    const float* beta_s  = (const float*)d_in[19];
    const float* rm_s    = (const float*)d_in[20];
    const float* rv_s    = (const float*)d_in[21];
    float* out = (float*)d_out;

    __hip_bfloat16* wsA    = (__hip_bfloat16*)((char*)d_ws + WSA_OFF);
    __hip_bfloat16* wsB    = (__hip_bfloat16*)((char*)d_ws + WSB_OFF);
    float*          ddp    = (float*)((char*)d_ws + DD_OFF);
    __hip_bfloat16* wsN    = (__hip_bfloat16*)((char*)d_ws + WN_OFF);
    float*          dnw    = (float*)((char*)d_ws + DN_OFF);
    __hip_bfloat16* featbf = (__hip_bfloat16*)((char*)d_ws + FB_OFF);
    __hip_bfloat16* rawA   = (__hip_bfloat16*)((char*)d_ws + RA_OFF);
    const int use_fb = (ws_size >= WS_FB) ? 1 : 0;
    const int use_ra = (ws_size >= WS_RA) ? 1 : 0;

    lfa_pre<<<4180, 256, 0, stream>>>(
        feature, rawn, w_attn,
        w_n, b_n, g_n, beta_n, rm_n, rv_n,
        w_o, b_o, g_o, beta_o, rm_o, rv_o,
        w_s, b_s, g_s, beta_s, rm_s, rv_s,
        featbf, rawA, wsA, wsB, ddp, wsN, dnw, use_fb, use_ra);

    const int nblocks = (4 * NPTS) / PB;   // 8192
    lfa_main<<<nblocks, 256, 0, stream>>>(
        feature, rawn, nidx,
        wsA, wsB, ddp, wsN, dnw, featbf, rawA, use_fb, use_ra, out);
}

// Round 8
// 301.187 us; speedup vs baseline: 1.0891x; 1.0891x over previous
//
#include <hip/hip_runtime.h>
#include <hip/hip_bf16.h>

typedef __attribute__((ext_vector_type(8))) short bf16x8;
typedef __attribute__((ext_vector_type(4))) float f32x4;

#define NPTS 8192
#define KNB  16
#define CG   10
#define CIN  128
#define CC   256
#define COUT 256
#define PB   4        // points per block
#define A2_LD 400     // a2S pitch in bf16 (800 B -> 8-dword bank stagger per row)

// d_ws layout (bytes)
#define WSA_OFF 0         // w_attn frags: 256x256 bf16 = 131072
#define WSB_OFF 131072    // W2 frags:    384x256 bf16 = 196608
#define DD_OFF  327680    // dd[256] fp32 = 1024
#define WN_OFF  328704    // w_n frags (an-folded, K=32 zero-pad): 8x64x8 bf16 = 8192
#define DN_OFF  336896    // dn_n[128] fp32 = 512
#define FB_OFF  524288    // featbf: 32768 x 128 bf16 = 8388608
#define RA_OFF  8912896   // rawA: 524288 rows x 32 bf16 (A-layout, K-pad) = 33554432
#define WS_FB   (FB_OFF + 8388608ull)
#define WS_RA   (RA_OFF + 33554432ull)

__device__ __forceinline__ short f2bs(float x) {
    __hip_bfloat16 h = __float2bfloat16(x);
    return *reinterpret_cast<short*>(&h);
}

// ---------------- pre: featbf cvt + rawA cvt + weight fragment packing ----------------
__global__ __launch_bounds__(256) void lfa_pre(
    const float* __restrict__ feature, const float* __restrict__ rawn,
    const float* __restrict__ w_attn,
    const float* __restrict__ w_n, const float* __restrict__ b_n,
    const float* __restrict__ g_n, const float* __restrict__ beta_n,
    const float* __restrict__ rm_n, const float* __restrict__ rv_n,
    const float* __restrict__ w_o, const float* __restrict__ b_o,
    const float* __restrict__ g_o, const float* __restrict__ beta_o,
    const float* __restrict__ rm_o, const float* __restrict__ rv_o,
    const float* __restrict__ w_s, const float* __restrict__ b_s,
    const float* __restrict__ g_s, const float* __restrict__ beta_s,
    const float* __restrict__ rm_s, const float* __restrict__ rv_s,
    __hip_bfloat16* __restrict__ featbf, __hip_bfloat16* __restrict__ rawA,
    __hip_bfloat16* __restrict__ wsA, __hip_bfloat16* __restrict__ wsB,
    float* __restrict__ dd,
    __hip_bfloat16* __restrict__ wsN, float* __restrict__ dnw,
    int use_fb, int use_ra)
{
    const int b = blockIdx.x, tid = threadIdx.x;
    if (b < 2048) {                      // featbf: fp32 -> bf16, 8 elems/thread
        if (!use_fb) return;
        size_t gid = (size_t)b * 256 + tid;
        const float4* src = (const float4*)(feature + gid * 8);
        float4 x = src[0], y = src[1];
        bf16x8 v;
        v[0] = f2bs(x.x); v[1] = f2bs(x.y); v[2] = f2bs(x.z); v[3] = f2bs(x.w);
        v[4] = f2bs(y.x); v[5] = f2bs(y.y); v[6] = f2bs(y.z); v[7] = f2bs(y.w);
        *(bf16x8*)(featbf + gid * 8) = v;
        return;
    }
    if (b < 4096) {                      // rawA: one (point,k) row per thread, K-pad to 32
        if (!use_ra) return;
        size_t row = (size_t)(b - 2048) * 256 + tid;     // 524288 rows
        const float* rb = rawn + row * CG;
        bf16x8 v0, v1, vz;
        #pragma unroll
        for (int j = 0; j < 8; ++j) vz[j] = 0;
        float2 a0 = *(const float2*)(rb + 0), a1 = *(const float2*)(rb + 2);
        float2 a2 = *(const float2*)(rb + 4), a3 = *(const float2*)(rb + 6);
        float2 a4 = *(const float2*)(rb + 8);
        v0[0] = f2bs(a0.x); v0[1] = f2bs(a0.y); v0[2] = f2bs(a1.x); v0[3] = f2bs(a1.y);
        v0[4] = f2bs(a2.x); v0[5] = f2bs(a2.y); v0[6] = f2bs(a3.x); v0[7] = f2bs(a3.y);
        v1 = vz; v1[0] = f2bs(a4.x); v1[1] = f2bs(a4.y);
        bf16x8* dst = (bf16x8*)(rawA + row * 32);
        dst[0] = v0; dst[1] = v1; dst[2] = vz; dst[3] = vz;
        return;
    }
    int gid = (b - 4096) * 256 + tid;    // weight packing
    if (gid < 8192) {                    // w_attn: 128 frags (kt 0..7, nt 0..15)
        int f = gid >> 6, l = gid & 63;
        int kt = f >> 4, nt = f & 15, q = l >> 4, c0 = l & 15;
        int col = nt * 16 + c0;
        bf16x8 v;
        #pragma unroll
        for (int j = 0; j < 8; ++j)
            v[j] = f2bs(w_attn[(kt * 32 + q * 8 + j) * CC + col]);
        *(bf16x8*)(wsA + (size_t)gid * 8) = v;
    } else if (gid < 8192 + 12288) {     // W2 = [w_s*a_s ; w_o*a_o]: 192 frags
        int g2 = gid - 8192;
        int f = g2 >> 6, l = g2 & 63;
        int kt = f >> 4, nt = f & 15, q = l >> 4, c0 = l & 15;
        int c = nt * 16 + c0;
        float as = g_s[c] * rsqrtf(rv_s[c] + 1e-5f);
        float ao = g_o[c] * rsqrtf(rv_o[c] + 1e-5f);
        bf16x8 v;
        #pragma unroll
        for (int j = 0; j < 8; ++j) {
            int r = kt * 32 + q * 8 + j;
            float x = (r < CIN) ? w_s[r * COUT + c] * as
                                : w_o[(r - CIN) * COUT + c] * ao;
            v[j] = f2bs(x);
        }
        *(bf16x8*)(wsB + (size_t)g2 * 8) = v;
    } else if (gid < 20736) {            // dd[c]
        int c = gid - 20480;
        float as = g_s[c] * rsqrtf(rv_s[c] + 1e-5f);
        float ao = g_o[c] * rsqrtf(rv_o[c] + 1e-5f);
        dd[c] = beta_s[c] + (b_s[c] - rm_s[c]) * as
              + beta_o[c] + (b_o[c] - rm_o[c]) * ao;
    } else if (gid < 21248) {            // w_n frags: an folded, K zero-pad to 32
        int g3 = gid - 20736;
        int nt = g3 >> 6, l = g3 & 63;
        int q = l >> 4, c0 = l & 15;
        int n = nt * 16 + c0;
        float an = g_n[n] * rsqrtf(rv_n[n] + 1e-5f);
        bf16x8 v;
        #pragma unroll
        for (int j = 0; j < 8; ++j) {
            int k = q * 8 + j;
            v[j] = (k < CG) ? f2bs(w_n[k * 128 + n] * an) : (short)0;
        }
        *(bf16x8*)(wsN + (size_t)g3 * 8) = v;
    } else if (gid < 21376) {            // dn_n[c]
        int c = gid - 21248;
        float an = g_n[c] * rsqrtf(rv_n[c] + 1e-5f);
        dnw[c] = beta_n[c] + (b_n[c] - rm_n[c]) * an;
    }
}

// ---------------- main fused kernel: PB points per block, 4 waves ----------------
// (256,3): ~170-reg budget. r7 lesson: am/wnb prefetched at kernel top were live
// across the whole gather phase -> compiler spilled ~160 MB/dispatch to scratch
// (WRITE_SIZE 191 MB vs 33 MB real). Loads now issue right before first use.
__global__ __launch_bounds__(256, 3) void lfa_main(
    const float* __restrict__ feature,   // [B,N,CIN] fp32
    const float* __restrict__ rawn,      // [B,N,K,CG]
    const int*   __restrict__ nidx,      // [B,N,K]
    const __hip_bfloat16* __restrict__ wsA,
    const __hip_bfloat16* __restrict__ wsB,
    const float* __restrict__ dd,
    const __hip_bfloat16* __restrict__ wsN,
    const float* __restrict__ dnw,
    const __hip_bfloat16* __restrict__ featbf,
    const __hip_bfloat16* __restrict__ rawA,
    int use_fb, int use_ra,
    float* __restrict__ out)             // [B,N,COUT]
{
    // catS: [64 rows][256 bf16], XOR-swizzled 16B chunks: chunk_phys = chunk ^ (row&7)
    __shared__ __align__(16) __hip_bfloat16 catS[64 * 256];   // 32768 B
    __shared__ __align__(16) __hip_bfloat16 a2S[4 * A2_LD];   // 3200 B

    const int tid  = threadIdx.x;
    const int lane = tid & 63;
    const int w    = tid >> 6;     // wave id 0..3
    const int q    = lane >> 4;    // quad 0..3
    const int c0   = lane & 15;
    const long long base0 = (long long)blockIdx.x * PB;   // identity mapping
    const long long bIdx  = base0 >> 13;                  // batch index (N=8192)

    // ---- phase 0b: center features -> a2S rows 0..3, cols 0..127
    if (use_fb) {
        if (tid < 64) {
            int p = tid >> 4, ch = tid & 15;
            *(bf16x8*)&a2S[p * A2_LD + ch * 8] =
                *(const bf16x8*)(featbf + (base0 + p) * CIN + ch * 8);
        }
    } else {
        int p = tid >> 6, cc = (tid & 63) * 2;
        const float* src = feature + (base0 + p) * CIN + cc;
        a2S[p * A2_LD + cc]     = __float2bfloat16(src[0]);
        a2S[p * A2_LD + cc + 1] = __float2bfloat16(src[1]);
    }
    // ---- phase 0c: gather neighbor features -> catS cols 0..127
    {
        int row = tid >> 2, qd = tid & 3;            // 64 rows x 4 quarters
        int ridx = nidx[base0 * KNB + row];          // 4-way dup -> L2 broadcast
        int sw = row & 7;
        if (use_fb) {
            const bf16x8* src = (const bf16x8*)(featbf + (bIdx * NPTS + ridx) * CIN + qd * 32);
            #pragma unroll
            for (int j = 0; j < 4; ++j)
                *(bf16x8*)&catS[row * 256 + (((qd * 4 + j) ^ sw) << 3)] = src[j];
        } else {
            const float4* src = (const float4*)(feature + (bIdx * NPTS + ridx) * CIN + qd * 32);
            #pragma unroll
            for (int j = 0; j < 4; ++j) {
                float4 x = src[2 * j], y = src[2 * j + 1];
                bf16x8 v;
                v[0] = f2bs(x.x); v[1] = f2bs(x.y); v[2] = f2bs(x.z); v[3] = f2bs(x.w);
                v[4] = f2bs(y.x); v[5] = f2bs(y.y); v[6] = f2bs(y.z); v[7] = f2bs(y.w);
                *(bf16x8*)&catS[row * 256 + (((qd * 4 + j) ^ sw) << 3)] = v;
            }
        }
    }

    // ---- phase 0d: neighbor MLP via MFMA -> catS cols 128..255
    // operand loads issue here (short live range; queue behind gather loads anyway)
    {
        bf16x8 wnb[2];
        #pragma unroll
        for (int i = 0; i < 2; ++i)
            wnb[i] = *(const bf16x8*)(wsN + (size_t)(((2 * w + i) * 64 + lane) * 8));
        bf16x8 am[4];
        if (use_ra) {
            #pragma unroll
            for (int mt = 0; mt < 4; ++mt)
                am[mt] = *(const bf16x8*)(rawA + (size_t)(base0 * 16 + mt * 16 + c0) * 32 + q * 8);
        } else {
            #pragma unroll
            for (int mt = 0; mt < 4; ++mt) {
                bf16x8 v;
                #pragma unroll
                for (int j = 0; j < 8; ++j) v[j] = 0;
                if (q == 0) {
                    const float* rb = rawn + ((base0 + mt) * KNB + c0) * CG;
                    #pragma unroll
                    for (int j = 0; j < 8; ++j) v[j] = f2bs(rb[j]);
                } else if (q == 1) {
                    const float* rb = rawn + ((base0 + mt) * KNB + c0) * CG + 8;
                    v[0] = f2bs(rb[0]); v[1] = f2bs(rb[1]);
                }
                am[mt] = v;
            }
        }
        const f32x4 vz = {0.f, 0.f, 0.f, 0.f};
        f32x4 cm[4][2];
        #pragma unroll
        for (int mt = 0; mt < 4; ++mt) { cm[mt][0] = vz; cm[mt][1] = vz; }
        #pragma unroll
        for (int mt = 0; mt < 4; ++mt)
            #pragma unroll
            for (int i = 0; i < 2; ++i)
                cm[mt][i] = __builtin_amdgcn_mfma_f32_16x16x32_bf16(am[mt], wnb[i], cm[mt][i], 0, 0, 0);
        #pragma unroll
        for (int i = 0; i < 2; ++i) {
            int c = (2 * w + i) * 16 + c0;      // MLP out channel 0..127
            float dnv = dnw[c];
            int col = CIN + c;
            #pragma unroll
            for (int mt = 0; mt < 4; ++mt)
                #pragma unroll
                for (int r = 0; r < 4; ++r) {
                    float y = cm[mt][i][r] + dnv;
                    y = (y >= 0.f) ? y : 0.2f * y;
                    int row = mt * 16 + q * 4 + r;
                    catS[row * 256 + ((((col >> 3) ^ (row & 7)) << 3)) + (col & 7)] =
                        __float2bfloat16(y);
                }
        }
    }
    __syncthreads();

    // ---- phase 1: logits GEMM  C[64 x 256] = cat[64 x 256] @ w_attn[256 x 256]
    const f32x4 vzero = {0.f, 0.f, 0.f, 0.f};
    f32x4 acc[4][4];
    #pragma unroll
    for (int mt = 0; mt < 4; ++mt)
        #pragma unroll
        for (int i = 0; i < 4; ++i) acc[mt][i] = vzero;

    #pragma unroll
    for (int kt = 0; kt < 8; ++kt) {
        bf16x8 bfr[4];
        #pragma unroll
        for (int i = 0; i < 4; ++i)
            bfr[i] = *(const bf16x8*)(wsA + (size_t)(((kt * 16 + 4 * w + i) * 64 + lane) * 8));
        bf16x8 af[4];
        #pragma unroll
        for (int mt = 0; mt < 4; ++mt)
            af[mt] = *(const bf16x8*)&catS[(mt * 16 + c0) * 256 + (((kt * 4 + q) ^ (c0 & 7)) << 3)];
        #pragma unroll
        for (int mt = 0; mt < 4; ++mt)
            #pragma unroll
            for (int i = 0; i < 4; ++i)
                acc[mt][i] = __builtin_amdgcn_mfma_f32_16x16x32_bf16(af[mt], bfr[i], acc[mt][i], 0, 0, 0);
    }

    // ---- phase 2: softmax over k (no max-sub; logits ~N(0,1)) + pooling
    // C layout: col = lane&15, row = q*4 + reg
    #pragma unroll
    for (int mt = 0; mt < 4; ++mt) {
        #pragma unroll
        for (int i = 0; i < 4; ++i) {
            f32x4 v = acc[mt][i];
            float e[4], s = 0.f;
            #pragma unroll
            for (int r = 0; r < 4; ++r) { e[r] = __expf(v[r]); s += e[r]; }
            s += __shfl_xor(s, 16);
            s += __shfl_xor(s, 32);
            int c = (4 * w + i) * 16 + c0;
            float pool = 0.f;
            #pragma unroll
            for (int r = 0; r < 4; ++r) {
                int row = mt * 16 + q * 4 + r;
                float cv = __bfloat162float(
                    catS[row * 256 + ((((c >> 3) ^ (row & 7)) << 3)) + (c & 7)]);
                pool += e[r] * cv;
            }
            pool += __shfl_xor(pool, 16);
            pool += __shfl_xor(pool, 32);
            if (q == mt) a2S[mt * A2_LD + CIN + c] =
                __float2bfloat16(pool * __builtin_amdgcn_rcpf(s));
        }
    }
    __syncthreads();

    // ---- phase 3: out GEMM  [4 x 256] = [feat|pooled][4 x 384] @ W2[384 x 256]
    f32x4 acc2[4];
    #pragma unroll
    for (int i = 0; i < 4; ++i) acc2[i] = vzero;
    #pragma unroll
    for (int kt = 0; kt < 12; ++kt) {
        bf16x8 a = *(const bf16x8*)&a2S[(c0 & 3) * A2_LD + kt * 32 + q * 8];
        #pragma unroll
        for (int i = 0; i < 4; ++i) {
            bf16x8 b = *(const bf16x8*)(wsB + (size_t)(((kt * 16 + 4 * w + i) * 64 + lane) * 8));
            acc2[i] = __builtin_amdgcn_mfma_f32_16x16x32_bf16(a, b, acc2[i], 0, 0, 0);
        }
    }
    // full-wave epilogue: quad q writes point q (select reg r=q)
    #pragma unroll
    for (int i = 0; i < 4; ++i) {
        int c = (4 * w + i) * 16 + c0;
        f32x4 t = acc2[i];
        float y = (q & 2) ? ((q & 1) ? t[3] : t[2]) : ((q & 1) ? t[1] : t[0]);
        y += dd[c];
        y = (y >= 0.f) ? y : 0.2f * y;
        out[(base0 + q) * COUT + c] = y;
    }
}

extern "C" void kernel_launch(void* const* d_in, const int* in_sizes, int n_in,
                              void* d_out, int out_size, void* d_ws, size_t ws_size,
                              hipStream_t stream) {
    const float* feature = (const float*)d_in[0];
    const float* rawn    = (const float*)d_in[1];
    const int*   nidx    = (const int*)d_in[2];
    const float* w_n     = (const float*)d_in[3];
    const float* b_n     = (const float*)d_in[4];
    const float* g_n     = (const float*)d_in[5];
    const float* beta_n  = (const float*)d_in[6];
    const float* rm_n    = (const float*)d_in[7];
    const float* rv_n    = (const float*)d_in[8];
    const float* w_attn  = (const float*)d_in[9];
    const float* w_o     = (const float*)d_in[10];
    const float* b_o     = (const float*)d_in[11];
    const float* g_o     = (const float*)d_in[12];
    const float* beta_o  = (const float*)d_in[13];
    const float* rm_o    = (const float*)d_in[14];
    const float* rv_o    = (const float*)d_in[15];
    const float* w_s     = (const float*)d_in[16];
    const float* b_s     = (const float*)d_in[17];
    const float* g_s     = (const float*)d_in[18];
    const float* beta_s  = (const float*)d_in[19];
    const float* rm_s    = (const float*)d_in[20];
    const float* rv_s    = (const float*)d_in[21];
    float* out = (float*)d_out;

    __hip_bfloat16* wsA    = (__hip_bfloat16*)((char*)d_ws + WSA_OFF);
    __hip_bfloat16* wsB    = (__hip_bfloat16*)((char*)d_ws + WSB_OFF);
    float*          ddp    = (float*)((char*)d_ws + DD_OFF);
    __hip_bfloat16* wsN    = (__hip_bfloat16*)((char*)d_ws + WN_OFF);
    float*          dnw    = (float*)((char*)d_ws + DN_OFF);
    __hip_bfloat16* featbf = (__hip_bfloat16*)((char*)d_ws + FB_OFF);
    __hip_bfloat16* rawA   = (__hip_bfloat16*)((char*)d_ws + RA_OFF);
    const int use_fb = (ws_size >= WS_FB) ? 1 : 0;
    const int use_ra = (ws_size >= WS_RA) ? 1 : 0;

    lfa_pre<<<4180, 256, 0, stream>>>(
        feature, rawn, w_attn,
        w_n, b_n, g_n, beta_n, rm_n, rv_n,
        w_o, b_o, g_o, beta_o, rm_o, rv_o,
        w_s, b_s, g_s, beta_s, rm_s, rv_s,
        featbf, rawA, wsA, wsB, ddp, wsN, dnw, use_fb, use_ra);

    const int nblocks = (4 * NPTS) / PB;   // 8192
    lfa_main<<<nblocks, 256, 0, stream>>>(
        feature, rawn, nidx,
        wsA, wsB, ddp, wsN, dnw, featbf, rawA, use_fb, use_ra, out);
}